// Round 1
// 881.051 us; speedup vs baseline: 1.2580x; 1.2580x over previous
//
#include <hip/hip_runtime.h>
#include <math.h>

#define B 4096
#define S 32
#define D 512
#define V 32000
#define H 256
#define ROWS 8
#define LN_EPS 1e-5f

// ws layout (floats):
// [0     .. 4096)  per-block entropy partials
// [4096  .. 8192)  per-block slot-norm partials
// [8192  .. 10240) per-block decision partials (512 blocks x 4)
// [16384 .. 16384+B*D) xn
#define WS_ENT  0
#define WS_NORM 4096
#define WS_DEC  8192
#define WS_XN   16384

__device__ __forceinline__ void combine3(float& m, float& a, float& bs,
                                         float m2, float a2, float b2) {
    float mn = fmaxf(m, m2);
    float c1 = __expf(m - mn);
    float c2 = __expf(m2 - mn);
    a  = a  * c1 + a2 * c2;
    bs = bs * c1 + b2 * c2;
    m  = mn;
}

__global__ __launch_bounds__(256) void entropy_kernel(
        const float* __restrict__ logits, float* __restrict__ ent_out) {
    const int row = blockIdx.x;
    const int t = threadIdx.x;
    const float4* v = (const float4*)(logits + (size_t)row * V);
    float m = -INFINITY, a = 0.f, bs = 0.f;
    for (int i = t; i < V / 4; i += 256) {
        float4 x = v[i];
        float mx = fmaxf(fmaxf(x.x, x.y), fmaxf(x.z, x.w));
        float mn = fmaxf(m, mx);
        float c  = __expf(m - mn);
        float e0 = __expf(x.x - mn);
        float e1 = __expf(x.y - mn);
        float e2 = __expf(x.z - mn);
        float e3 = __expf(x.w - mn);
        a  = a  * c + (e0 + e1 + e2 + e3);
        bs = bs * c + (x.x * e0 + x.y * e1 + x.z * e2 + x.w * e3);
        m  = mn;
    }
    // wave64 shuffle reduction
    for (int off = 32; off >= 1; off >>= 1) {
        float m2 = __shfl_down(m, off);
        float a2 = __shfl_down(a, off);
        float b2 = __shfl_down(bs, off);
        combine3(m, a, bs, m2, a2, b2);
    }
    __shared__ float sm[4], sa[4], sb[4];
    const int wave = t >> 6, lane = t & 63;
    if (lane == 0) { sm[wave] = m; sa[wave] = a; sb[wave] = bs; }
    __syncthreads();
    if (t == 0) {
        m = sm[0]; a = sa[0]; bs = sb[0];
        for (int w = 1; w < 4; w++) combine3(m, a, bs, sm[w], sa[w], sb[w]);
        ent_out[row] = (m + logf(a)) - bs / a;   // per-block partial, no atomic
    }
}

__global__ __launch_bounds__(256) void slots_kernel(
        const float* __restrict__ slots,
        const float* __restrict__ ln_w, const float* __restrict__ ln_b,
        float* __restrict__ norm_out, float* __restrict__ xn_out) {
    const int b = blockIdx.x;
    const int t = threadIdx.x;
    const int wave = t >> 6, lane = t & 63;
    const float* base = slots + (size_t)b * S * D;

    float col[8];
#pragma unroll
    for (int j = 0; j < 8; j++) col[j] = 0.f;
    float normsum = 0.f;

    for (int i = 0; i < 8; i++) {
        int s = wave + i * 4;                 // waves cover all 32 s-values
        const float* row = base + s * D + lane * 8;
        float4 v0 = *(const float4*)(row);
        float4 v1 = *(const float4*)(row + 4);
        col[0] += v0.x; col[1] += v0.y; col[2] += v0.z; col[3] += v0.w;
        col[4] += v1.x; col[5] += v1.y; col[6] += v1.z; col[7] += v1.w;
        float sq = v0.x*v0.x + v0.y*v0.y + v0.z*v0.z + v0.w*v0.w
                 + v1.x*v1.x + v1.y*v1.y + v1.z*v1.z + v1.w*v1.w;
        for (int off = 32; off >= 1; off >>= 1) sq += __shfl_down(sq, off);
        if (lane == 0) normsum += sqrtf(sq);
    }

    __shared__ float xs[4 * D];               // 8 KB: per-wave column partials
    __shared__ float nw[4];
    if (lane == 0) nw[wave] = normsum;
#pragma unroll
    for (int j = 0; j < 8; j++) xs[wave * D + lane * 8 + j] = col[j];
    __syncthreads();
    if (t == 0)                                // one partial per block, no atomic
        norm_out[b] = nw[0] + nw[1] + nw[2] + nw[3];

    // each thread owns columns t and t+256
    const int t2 = t + 256;
    float x0 = (xs[t]  + xs[D + t]  + xs[2*D + t]  + xs[3*D + t])  * (1.f / S);
    float x1 = (xs[t2] + xs[D + t2] + xs[2*D + t2] + xs[3*D + t2]) * (1.f / S);

    // LayerNorm stats over 512 via block reduce
    float s1 = x0 + x1, s2 = x0 * x0 + x1 * x1;
    for (int off = 32; off >= 1; off >>= 1) {
        s1 += __shfl_down(s1, off);
        s2 += __shfl_down(s2, off);
    }
    __shared__ float r1[4], r2[4];
    if (lane == 0) { r1[wave] = s1; r2[wave] = s2; }
    __syncthreads();
    s1 = r1[0] + r1[1] + r1[2] + r1[3];
    s2 = r2[0] + r2[1] + r2[2] + r2[3];
    float mu  = s1 * (1.f / D);
    float var = s2 * (1.f / D) - mu * mu;
    float inv = rsqrtf(var + LN_EPS);
    xn_out[(size_t)b * D + t]  = (x0 - mu) * inv * ln_w[t]  + ln_b[t];
    xn_out[(size_t)b * D + t2] = (x1 - mu) * inv * ln_w[t2] + ln_b[t2];
}

__global__ __launch_bounds__(256) void mlp_kernel(
        const float* __restrict__ xn,
        const float* __restrict__ w1, const float* __restrict__ b1,
        const float* __restrict__ w2, const float* __restrict__ b2,
        float* __restrict__ dec_out) {
    __shared__ float xl[ROWS * D];            // 16 KB
    __shared__ float hl[ROWS * H];            // 8 KB
    __shared__ float ps[ROWS * 4];
    const int t = threadIdx.x;
    const size_t rb = (size_t)blockIdx.x * ROWS;
    for (int i = t; i < ROWS * D; i += 256) xl[i] = xn[rb * D + i];
    __syncthreads();

    float accr[ROWS];
    float bias = b1[t];
#pragma unroll
    for (int r = 0; r < ROWS; r++) accr[r] = bias;
    for (int k = 0; k < D; k++) {
        float w = w1[t * D + k];
#pragma unroll
        for (int r = 0; r < ROWS; r++) accr[r] += w * xl[r * D + k];
    }
#pragma unroll
    for (int r = 0; r < ROWS; r++) {
        float aH = accr[r];
        // exact GELU: 0.5*x*(1+erf(x/sqrt(2)))
        float g = 0.5f * aH * (1.f + erff(aH * 0.70710678118654752f));
        hl[r * H + t] = g;
    }
    __syncthreads();
    if (t < ROWS * 4) {
        int r = t >> 2, o = t & 3;
        float d = b2[o];
        for (int k = 0; k < H; k++) d += hl[r * H + k] * w2[o * H + k];
        ps[t] = 1.f / (1.f + __expf(-d));
    }
    __syncthreads();
    if (t < 4) {                               // one partial vec per block
        float d = 0.f;
#pragma unroll
        for (int r = 0; r < ROWS; r++) d += ps[r * 4 + t];
        dec_out[(size_t)blockIdx.x * 4 + t] = d;
    }
}

__global__ __launch_bounds__(256) void finalize_kernel(
        const float* __restrict__ ws, float* __restrict__ out) {
    const int t = threadIdx.x;
    const int wave = t >> 6, lane = t & 63;
    float es = 0.f, ns = 0.f;
    for (int i = t; i < B; i += 256) {
        es += ws[WS_ENT + i];
        ns += ws[WS_NORM + i];
    }
    for (int off = 32; off >= 1; off >>= 1) {
        es += __shfl_down(es, off);
        ns += __shfl_down(ns, off);
    }
    __shared__ float se[4], sn[4], sd[256];
    if (lane == 0) { se[wave] = es; sn[wave] = ns; }

    // decision partials: 512 blocks x 4; thread t handles o=t&3, blocks t>>2 + j*64
    float ds = 0.f;
    for (int blk = (t >> 2); blk < (B / ROWS); blk += 64)
        ds += ws[WS_DEC + blk * 4 + (t & 3)];
    sd[t] = ds;
    __syncthreads();
    if (t < 4) {
        float d = 0.f;
        for (int i = t; i < 256; i += 4) d += sd[i];
        out[t] = d * (1.f / B);
    } else if (t == 4) {
        out[4] = (se[0] + se[1] + se[2] + se[3]) * (1.f / B);
    } else if (t == 5) {
        out[5] = (sn[0] + sn[1] + sn[2] + sn[3]) * (1.f / (B * S));
    }
}

extern "C" void kernel_launch(void* const* d_in, const int* in_sizes, int n_in,
                              void* d_out, int out_size, void* d_ws, size_t ws_size,
                              hipStream_t stream) {
    const float* slots  = (const float*)d_in[0];
    const float* logits = (const float*)d_in[1];
    const float* ln_w   = (const float*)d_in[2];
    const float* ln_b   = (const float*)d_in[3];
    const float* w1     = (const float*)d_in[4];
    const float* b1     = (const float*)d_in[5];
    const float* w2     = (const float*)d_in[6];
    const float* b2     = (const float*)d_in[7];
    float* out = (float*)d_out;
    float* ws  = (float*)d_ws;
    float* xn  = ws + WS_XN;

    entropy_kernel<<<B, 256, 0, stream>>>(logits, ws + WS_ENT);
    slots_kernel<<<B, 256, 0, stream>>>(slots, ln_w, ln_b, ws + WS_NORM, xn);
    mlp_kernel<<<B / ROWS, 256, 0, stream>>>(xn, w1, b1, w2, b2, ws + WS_DEC);
    finalize_kernel<<<1, 256, 0, stream>>>(ws, out);
}